// Round 1
// baseline (2309.624 us; speedup 1.0000x reference)
//
#include <hip/hip_runtime.h>

// Problem: VQ-VAE codebook. z [32,256,32,32] f32, emb [8192,256] f32.
// Outputs concatenated in d_out (f32): z_q [8388608], idx [32768] (as float), loss [1].
//
// Scratch layout inside d_out's z_q region (consumed before k_out overwrites it):
//   [0 .. 2097152)        embT  (256 x 8192)   transposed codebook
//   [2097152 .. 2105344)  se    (8192)         ||e_k||^2
//   [2105344 .. 2138112)  sz    (32768)        ||z_n||^2
#define ZQ_OFF   0
#define EMBT_OFF 0
#define SE_OFF   2097152
#define SZ_OFF   2105344
#define IDX_OFF  8388608
#define LOSS_OFF 8421376

// ---- transpose emb -> embT[d][k] (coalesced writes, scattered reads; 8 MB, tiny)
__global__ void k_prep_transpose(const float* __restrict__ emb, float* __restrict__ embT) {
    int u = blockIdx.x * 256 + threadIdx.x;      // 0 .. 2M, grid = 8192 blocks
    int d = u >> 13;
    int k = u & 8191;
    embT[u] = emb[(size_t)k * 256 + d];
}

// ---- se[k] = sum(emb[k]^2)  (order-insensitive; wave per code, butterfly reduce)
__global__ void k_se(const float* __restrict__ emb, float* __restrict__ se) {
    int w    = (blockIdx.x * 256 + threadIdx.x) >> 6;   // code id
    int lane = threadIdx.x & 63;
    float4 v = *(const float4*)(emb + (size_t)w * 256 + lane * 4);
    float s = v.x * v.x + v.y * v.y + v.z * v.z + v.w * v.w;
    #pragma unroll
    for (int off = 1; off < 64; off <<= 1) s += __shfl_xor(s, off);
    if (lane == 0) se[w] = s;
}

// ---- sz[n] = sum over c of z[b][c][hw]^2 (order-insensitive: same-binade shift invariance)
__global__ void k_sz(const float* __restrict__ z, float* __restrict__ sz) {
    int n  = blockIdx.x * 256 + threadIdx.x;  // grid = 128 blocks
    int b  = n >> 10, hw = n & 1023;
    const float* zp = z + (size_t)b * 262144 + hw;
    float acc = 0.f;
    #pragma unroll 8
    for (int c = 0; c < 256; ++c) { float v = zp[(size_t)c << 10]; acc += v * v; }
    sz[n] = acc;
}

// ---- main: exact-f32-replica distance + argmin
// 512 threads, 64 rows/block. Wave w (i = tid>>6) owns rows i*8..i*8+7; lane j = tid&63
// owns codes (tile*256 + j*4 .. +3) across 32 tiles of 256 codes.
// Per-thread work identical to previous version (R=8, C=4, same fmaf chain order),
// but 4 waves/SIMD resident (vs 2) to hide embT L2/L3-miss latency.
// d_nk = fl( fl(sz_n + se_k) - 2*m_nk ),  m = sequential fmaf chain over d=0..255 (BLAS order)
__global__ __launch_bounds__(512, 4) void k_main(
    const float* __restrict__ z, const float* __restrict__ embT,
    const float* __restrict__ se, const float* __restrict__ sz,
    float* __restrict__ idxf, float* __restrict__ lossslot) {
    __shared__ float zt[64][256];
    const int tid = threadIdx.x;
    const int blk = blockIdx.x;            // grid = 512
    const int n0  = blk * 64;
    const int b   = n0 >> 10, hw0 = n0 & 1023;

    // stage z tile (NCHW gather -> LDS [row][c]); coalesced global reads over rows
    {
        const int n  = tid & 63;
        const int cg = tid >> 6;                        // 0..7
        const float* zp = z + (size_t)b * 262144 + hw0 + n;
        for (int cc = 0; cc < 256; cc += 8)
            zt[n][cc + cg] = zp[(size_t)(cc + cg) << 10];
    }
    __syncthreads();

    const int i = tid >> 6;       // wave-uniform row group 0..7 -> rows i*8 .. i*8+7
    const int j = tid & 63;       // code lane -> codes tile*256 + j*4 ..
    float szr[8];
    #pragma unroll
    for (int r = 0; r < 8; ++r) szr[r] = sz[n0 + i * 8 + r];

    float bestd[8]; int bestk[8];
    #pragma unroll
    for (int r = 0; r < 8; ++r) { bestd[r] = 3.4e38f; bestk[r] = 0; }

    for (int tile = 0; tile < 32; ++tile) {
        const int c0 = tile * 256 + j * 4;
        float acc[8][4];
        #pragma unroll
        for (int r = 0; r < 8; ++r)
            #pragma unroll
            for (int c = 0; c < 4; ++c) acc[r][c] = 0.f;

        #pragma unroll 2
        for (int t = 0; t < 64; ++t) {                 // d-chunks of 4, ascending
            float4 ef[4];
            #pragma unroll
            for (int dd = 0; dd < 4; ++dd)
                ef[dd] = *(const float4*)(embT + (size_t)(t * 4 + dd) * 8192 + c0);
            float4 zr[8];
            #pragma unroll
            for (int r = 0; r < 8; ++r)
                zr[r] = *(const float4*)(&zt[i * 8 + r][t * 4]);
            #pragma unroll
            for (int dd = 0; dd < 4; ++dd) {
                #pragma unroll
                for (int r = 0; r < 8; ++r) {
                    const float zv = ((const float*)&zr[r])[dd];
                    #pragma unroll
                    for (int c = 0; c < 4; ++c)
                        acc[r][c] = fmaf(zv, ((const float*)&ef[dd])[c], acc[r][c]);
                }
            }
        }
        // epilogue: replicate fl(fl(sz+se) - 2m); ascending c per row; strict < keeps first min
        const float4 se4 = *(const float4*)(se + c0);
        #pragma unroll
        for (int c = 0; c < 4; ++c) {
            const float sek = ((const float*)&se4)[c];
            #pragma unroll
            for (int r = 0; r < 8; ++r) {
                float A  = szr[r] + sek;
                float dq = A - 2.0f * acc[r][c];
                if (dq < bestd[r]) { bestd[r] = dq; bestk[r] = c0 + c; }
            }
        }
    }
    // reduce across the 64 j-lanes (full wave); tie-break lowest k
    #pragma unroll
    for (int r = 0; r < 8; ++r) {
        float d = bestd[r]; int k = bestk[r];
        #pragma unroll
        for (int off = 1; off < 64; off <<= 1) {
            float od = __shfl_xor(d, off);
            int   ok = __shfl_xor(k, off);
            if (od < d || (od == d && ok < k)) { d = od; k = ok; }
        }
        if (j == 0) idxf[n0 + i * 8 + r] = (float)k;
    }
    if (blk == 0 && tid == 0) *lossslot = 0.f;   // init loss accumulator (runs before k_out)
}

// ---- z_q (STE-exact) + loss partial sums
__global__ void k_out(const float* __restrict__ z, const float* __restrict__ emb,
                      const float* __restrict__ idxf, float* __restrict__ zq,
                      float* __restrict__ lossslot) {
    int u   = blockIdx.x * 256 + threadIdx.x;   // grid = 8192 blocks (2M threads)
    int cc4 = u >> 15;                          // 0..63 (uniform per block)
    int n   = u & 32767;
    int b   = n >> 10, hw = n & 1023;
    int k   = (int)idxf[n];
    const float4 q4 = *(const float4*)(emb + (size_t)k * 256 + cc4 * 4);
    float ls = 0.f;
    #pragma unroll
    for (int c = 0; c < 4; ++c) {
        size_t zi = (size_t)b * 262144 + (size_t)(cc4 * 4 + c) * 1024 + hw;
        float zv   = z[zi];
        float qv   = ((const float*)&q4)[c];
        float diff = qv - zv;        // fl(q - z)
        zq[zi]     = zv + diff;      // fl(z + fl(q - z))  == reference STE output
        ls += diff * diff;
    }
    #pragma unroll
    for (int off = 1; off < 64; off <<= 1) ls += __shfl_xor(ls, off);
    if ((threadIdx.x & 63) == 0) atomicAdd(lossslot, ls);
}

__global__ void k_fin(float* __restrict__ lossslot) {
    float S = *lossslot;
    float m = S / 8388608.0f;        // /2^23 exact scaling
    *lossslot = m + 0.25f * m;       // fl(m1 + fl(beta*m2)), m1==m2
}

extern "C" void kernel_launch(void* const* d_in, const int* in_sizes, int n_in,
                              void* d_out, int out_size, void* d_ws, size_t ws_size,
                              hipStream_t stream) {
    const float* z   = (const float*)d_in[0];
    const float* emb = (const float*)d_in[1];
    float* out  = (float*)d_out;
    float* embT = out + EMBT_OFF;
    float* se   = out + SE_OFF;
    float* sz   = out + SZ_OFF;
    float* idxf = out + IDX_OFF;
    float* loss = out + LOSS_OFF;

    k_prep_transpose<<<8192, 256, 0, stream>>>(emb, embT);
    k_se<<<2048, 256, 0, stream>>>(emb, se);
    k_sz<<<128, 256, 0, stream>>>(z, sz);
    k_main<<<512, 512, 0, stream>>>(z, embT, se, sz, idxf, loss);
    k_out<<<8192, 256, 0, stream>>>(z, emb, idxf, out + ZQ_OFF, loss);
    k_fin<<<1, 1, 0, stream>>>(loss);
}